// Round 7
// baseline (1296.503 us; speedup 1.0000x reference)
//
#include <hip/hip_runtime.h>
#include <hip/hip_cooperative_groups.h>
#include <hip/hip_fp16.h>
#include <math.h>

namespace cg = cooperative_groups;

#define HH 512
#define WW 512
#define BB 4
#define NPIX (BB * HH * WW)

#define HS 4                 // core rows per wave (R0 % 4 == 0)
#define NSX 9                // strips: 9 x 60 core cols >= 512
#define NBAND (HH / HS)      // 128
#define NWAVES (NSX * NBAND * BB)   // 4608
#define NBLK (NWAVES / 4)           // 1152

constexpr float TAUf   = 0.01f;
constexpr float RHOf   = 1.99f;
constexpr float SIGMAf = (float)(1.0 / 0.01 / 72.0);
constexpr float INV1PT = (float)(1.0 / 1.01);

__device__ __forceinline__ float SD(float v) { return __shfl_down(v, 1, 64); }  // lane+1
__device__ __forceinline__ float SUp(float v) { return __shfl_up(v, 1, 64); }   // lane-1

// Fused state record F (uint2): .x = half2(x2, r0), .y = half2(r1, y_half)
// y_half bits pass through unchanged every iteration (no re-rounding drift).

// ---------------------------------------------------------------------------
// Per-iteration body, shared by both the fused cooperative kernel and the
// per-dispatch fallback. IT: 0 = init, 1 = mid, 2 = final (x-only, f32 out).
// ---------------------------------------------------------------------------
template <int IT>
__device__ __forceinline__ void iter_body(
    const float* __restrict__ y,
    const uint2* __restrict__ fi, const uint2* __restrict__ ui,
    uint2* __restrict__ fo, uint2* __restrict__ uo,
    float* __restrict__ xout,
    int R0, int w, int boff, bool wok, float mA, float mB, bool cok,
    float tl1_, float l2_)
{
    float uf0[4], uf1[4], uf2[4], uf3[4];
    float i0r[2], i1r[2];
    float sr[2], t1r[2];
    float v0r[4], v1r[2];
    #pragma unroll
    for (int q = 0; q < 4; ++q) { uf0[q]=uf1[q]=uf2[q]=uf3[q]=0.f; v0r[q]=0.f; }
    i0r[0]=i0r[1]=i1r[0]=i1r[1]=0.f;
    sr[0]=sr[1]=0.f; t1r[0]=t1r[1]=0.f; v1r[0]=v1r[1]=0.f;

    auto uload = [&](int row) -> uint2 {
        uint2 z; z.x = 0u; z.y = 0u;
        if (((unsigned)row) < (unsigned)HH && wok)
            z = ui[(size_t)(boff + row * WW + w)];
        return z;
    };
    auto fload = [&](int row) -> uint2 {
        uint2 z; z.x = 0u; z.y = 0u;
        if (((unsigned)row) < (unsigned)HH && wok)
            z = fi[(size_t)(boff + row * WW + w)];
        return z;
    };
    auto unpk = [&](int slot, uint2 raw) {
        __half2 lo = *(reinterpret_cast<__half2*>(&raw.x));
        __half2 hi = *(reinterpret_cast<__half2*>(&raw.y));
        uf0[slot] = __low2float(lo); uf1[slot] = __high2float(lo);
        uf2[slot] = __low2float(hi); uf3[slot] = __high2float(hi);
    };
    auto compI = [&](int rr, int islot, int c, int d, int uu_) {
        if (((unsigned)rr) < (unsigned)HH) {
            float hD  = (rr < HH - 1) ? 1.f : 0.f;
            float u1c = uf1[c], u2c = uf2[c];
            i0r[islot] = uf0[c] - uf0[d] - SD(u1c) + mA * u1c;
            i1r[islot] = u2c - SD(u2c) - hD * uf3[c] + uf3[uu_];
        } else { i0r[islot] = 0.f; i1r[islot] = 0.f; }
    };

    if (IT == 2) {
        // ---- final iter: x-only, f32 out, 2-deep prefetch ----
        unpk(2, uload(R0 - 2));
        unpk(3, uload(R0 - 1));
        unpk(0, uload(R0));
        compI(R0 - 1, 1, 3, 0, 2);
        uint2 puA = uload(R0 + 1);
        uint2 puB = uload(R0 + 2);
        uint2 pfA = fload(R0);
        uint2 pfB = fload(R0 + 1);
        #pragma unroll
        for (int k = 0; k < HS; ++k) {
            const int rr = R0 + k;
            unpk((k + 1) & 3, puA);
            puA = puB;
            if (k < HS - 2) puB = uload(R0 + k + 3);
            __half2 lo = *(reinterpret_cast<__half2*>(&pfA.x));
            __half2 hi = *(reinterpret_cast<__half2*>(&pfA.y));
            float x2v = __low2float(lo);
            float yv  = __high2float(hi);
            pfA = pfB;
            if (k < HS - 2) pfB = fload(R0 + k + 2);
            compI(rr, k & 1, k & 3, (k + 1) & 3, (k + 3) & 3);
            float hD = (rr < HH - 1) ? 1.f : 0.f;
            float i0c = i0r[k & 1], i1c = i1r[k & 1], i1u = i1r[(k + 1) & 1];
            float i0l = SUp(i0c);
            float na = TAUf * (mA * i0l - mB * i0c + i1u - hD * i1c);
            float x = (x2v - na + TAUf * yv) * INV1PT;
            if (cok) xout[boff + rr * WW + w] = x2v + RHOf * (x - x2v);
        }
        return;
    }

    const bool init = (IT == 0);

    uint2 puA, puB, pfA, pfB;
    puA.x = puA.y = puB.x = puB.y = 0u;
    pfA.x = pfA.y = pfB.x = pfB.y = 0u;
    float pyA = 0.f, pyB = 0.f;
    if (!init) {
        unpk(1, uload(R0 - 3));
        unpk(2, uload(R0 - 2));
        unpk(3, uload(R0 - 1));
        compI(R0 - 2, 0, 2, 3, 1);
        puA = uload(R0);
        puB = uload(R0 + 1);
        pfA = fload(R0 - 1);
        pfB = fload(R0);
    } else {
        int rowA = R0 - 1; bool okA = (((unsigned)rowA) < (unsigned)HH) && wok;
        pyA = okA ? y[boff + rowA * WW + w] : 0.f;
        pyB = wok ? y[boff + R0 * WW + w] : 0.f;   // row R0 always valid
    }

    #pragma unroll
    for (int k = 0; k < HS + 3; ++k) {
        const int rr = R0 - 1 + k;
        float yv, x2v = 0.f, r20v = 0.f, r21v = 0.f; unsigned yraw = 0u;
        if (!init) {
            unpk(k & 3, puA);
            puA = puB;
            if (k <= HS) puB = uload(R0 + k + 2);
            __half2 lo = *(reinterpret_cast<__half2*>(&pfA.x));
            __half2 hi = *(reinterpret_cast<__half2*>(&pfA.y));
            x2v  = __low2float(lo);  r20v = __high2float(lo);
            r21v = __low2float(hi);  yv   = __high2float(hi);
            yraw = pfA.y >> 16;
            pfA = pfB;
            if (k <= HS) pfB = fload(R0 + k + 1);
        } else {
            yv = pyA;
            pyA = pyB;
            if (k <= HS) {
                int row = R0 + k + 1;
                bool ok = (((unsigned)row) < (unsigned)HH) && wok;
                pyB = ok ? y[boff + row * WW + w] : 0.f;
            }
        }
        if (!init) compI(rr, (k + 1) & 1, (k + 3) & 3, k & 3, (k + 2) & 3);

        // compS: s,t(rr); relax writes on core rows
        float sN, t0N, t1N;
        {
            const bool coreRow = (k >= 1 && k <= HS);
            if (((unsigned)rr) < (unsigned)HH) {
                if (init) {
                    sN = yv; t0N = 0.f; t1N = 0.f;
                    if (coreRow && cok) {
                        int idx = boff + rr * WW + w;
                        unsigned hb = (unsigned)__half_as_ushort(__float2half(yv));
                        uint2 st; st.x = hb; st.y = hb << 16;  // {x2=y,r0=0,r1=0,y}
                        fo[(size_t)idx] = st;
                    }
                } else {
                    float hD = (rr < HH - 1) ? 1.f : 0.f;
                    float i0c = i0r[(k + 1) & 1], i1c = i1r[(k + 1) & 1];
                    float i1u = i1r[k & 1];
                    float i0l = SUp(i0c);
                    float na = TAUf * (mA * i0l - mB * i0c + i1u - hD * i1c);
                    float x = (x2v - na + TAUf * yv) * INV1PT;
                    float rr0 = r20v + TAUf * i0c;
                    float rr1 = r21v + TAUf * i1c;
                    float d = rr0 * rr0 + rr1 * rr1;
                    float rinv = fminf(tl1_ * __builtin_amdgcn_rsqf(d), 1.0f);
                    float r0 = rr0 - rr0 * rinv;
                    float r1 = rr1 - rr1 * rinv;
                    sN  = 2.f * x  - x2v;
                    t0N = 2.f * r0 - r20v;
                    t1N = 2.f * r1 - r21v;
                    if (coreRow && cok) {
                        int idx = boff + rr * WW + w;
                        __half2 lo2 = __floats2half2_rn(x2v + RHOf * (x - x2v),
                                                        r20v + RHOf * (r0 - r20v));
                        unsigned r1b = (unsigned)__half_as_ushort(
                            __float2half(r21v + RHOf * (r1 - r21v)));
                        uint2 st; st.x = *(unsigned*)&lo2; st.y = r1b | (yraw << 16);
                        fo[(size_t)idx] = st;
                    }
                }
            } else { sN = 0.f; t0N = 0.f; t1N = 0.f; }
        }

        // v-ring updates for row rr (v0) and row rr-1 (v1)
        {
            float sPrev  = sr[k & 1];
            float t1Prev = t1r[k & 1];
            float hDm1   = (rr < HH) ? 1.f : 0.f;
            v0r[(k + 3) & 3] = mB * (SD(sN) - sN) - t0N;
            v1r[k & 1]       = hDm1 * (sN - sPrev) - t1Prev;
            sr[(k + 1) & 1]  = sN;
            t1r[(k + 1) & 1] = t1N;
        }

        if (k >= 3) {
            const int ro = R0 - 3 + k;
            float hD  = (ro < HH - 1) ? 1.f : 0.f;
            float v0c = v0r[(k + 1) & 3], v0u = v0r[k & 3];
            float v1c = v1r[(k + 1) & 1], v1d = v1r[k & 1];
            float v0l = SUp(v0c);
            float v1l = SUp(v1c);
            float G0 = v0c - v0u;
            float G1 = mA * (v0c - v0l);
            float G2 = v1c - mA * v1l;
            float G3 = hD * (v1d - v1c);
            float u0v, u1v, u2v, u3v;
            if (init) { u0v = u1v = u2v = u3v = 0.f; }
            else {
                const int us = (k + 1) & 3;
                u0v = uf0[us]; u1v = uf1[us]; u2v = uf2[us]; u3v = uf3[us];
            }
            float uu0 = u0v + SIGMAf * G0;
            float uu1 = u1v + SIGMAf * G1;
            float uu2 = u2v + SIGMAf * G2;
            float uu3 = u3v + SIGMAf * G3;
            float d = uu0 * uu0 + uu1 * uu1 + uu2 * uu2 + uu3 * uu3;
            float uiS = fminf(l2_ * __builtin_amdgcn_rsqf(d), 1.0f);
            if (cok) {
                int idx = boff + ro * WW + w;
                __half2 lo = __floats2half2_rn(u0v + RHOf * (uu0 * uiS - u0v),
                                               u1v + RHOf * (uu1 * uiS - u1v));
                __half2 hi = __floats2half2_rn(u2v + RHOf * (uu2 * uiS - u2v),
                                               u3v + RHOf * (uu3 * uiS - u3v));
                uint2 st; st.x = *(unsigned*)&lo; st.y = *(unsigned*)&hi;
                uo[(size_t)idx] = st;
            }
        }
    }
}

#define WAVE_GEOM                                                    \
    const int tid  = threadIdx.x;                                    \
    const int lane = tid & 63;                                       \
    const int wid  = blockIdx.x * 4 + (tid >> 6);                    \
    const int sx   = wid % NSX;                                      \
    const int t2   = wid / NSX;                                      \
    const int band = t2 & (NBAND - 1);                               \
    const int b    = t2 / NBAND;                                     \
    const int R0   = band * HS;                                      \
    const int w    = sx * 60 - 2 + lane;                             \
    const int boff = b * (HH * WW);                                  \
    const bool wok = ((unsigned)w) < (unsigned)WW;                   \
    const float mA = (w >= 1 && w < WW) ? 1.f : 0.f;                 \
    const float mB = (w >= 0 && w < WW - 1) ? 1.f : 0.f;             \
    const bool cok = (lane >= 2) && (lane < 62) && (w < WW);         \
    const float ths  = (float)ths_p[0];                              \
    const float tl1_ = TAUf * (ths * 0.1f);                          \
    const float l2_  = ths * 0.15f;

// ---- fused cooperative kernel: all 10 iterations, grid.sync between ----
__global__ __launch_bounds__(256, 5) void fused(
    const float* __restrict__ y, const int* __restrict__ ths_p,
    uint2* __restrict__ FA, uint2* __restrict__ UA,
    uint2* __restrict__ FB, uint2* __restrict__ UB,
    float* __restrict__ xout)
{
    cg::grid_group gg = cg::this_grid();
    WAVE_GEOM

    const uint2* fi = FB; const uint2* ui = UB;
    uint2* fo = FB; uint2* uo = UB;           // iter 0 writes B (reads nothing)

    iter_body<0>(y, fi, ui, fo, uo, xout, R0, w, boff, wok, mA, mB, cok, tl1_, l2_);
    gg.sync();
    fi = fo; ui = uo; fo = FA; uo = UA;
    for (int it = 1; it <= 8; ++it) {
        iter_body<1>(y, fi, ui, fo, uo, xout, R0, w, boff, wok, mA, mB, cok, tl1_, l2_);
        gg.sync();
        const uint2* tf = fi; fi = fo; fo = (uint2*)tf;
        const uint2* tu = ui; ui = uo; uo = (uint2*)tu;
    }
    iter_body<2>(y, fi, ui, nullptr, nullptr, xout, R0, w, boff, wok, mA, mB, cok, tl1_, l2_);
}

// ---- fallback: one dispatch per iteration (proven 160 µs path) ----
template <int MODE>
__global__ __launch_bounds__(256) void sweep(
    const float* __restrict__ y, const int* __restrict__ ths_p,
    const uint2* __restrict__ f_in, const uint2* __restrict__ u_in,
    uint2* __restrict__ f_out, uint2* __restrict__ u_out,
    float* __restrict__ xout)
{
    WAVE_GEOM
    iter_body<MODE>(y, f_in, u_in, f_out, u_out, xout,
                    R0, w, boff, wok, mA, mB, cok, tl1_, l2_);
}

extern "C" void kernel_launch(void* const* d_in, const int* in_sizes, int n_in,
                              void* d_out, int out_size, void* d_ws, size_t ws_size,
                              hipStream_t stream)
{
    const float* y   = (const float*)d_in[0];
    const int*   ths = (const int*)d_in[1];
    uint2* ws2 = (uint2*)d_ws;

    uint2* FA = ws2;
    uint2* UA = ws2 + (size_t)NPIX;
    uint2* FB = ws2 + 2 * (size_t)NPIX;
    uint2* UB = ws2 + 3 * (size_t)NPIX;
    float* xout = (float*)d_out;

    void* args[] = { (void*)&y, (void*)&ths, (void*)&FA, (void*)&UA,
                     (void*)&FB, (void*)&UB, (void*)&xout };
    hipError_t err = hipLaunchCooperativeKernel((void*)fused, dim3(NBLK), dim3(256),
                                                args, 0, stream);
    if (err != hipSuccess) {
        // graceful fallback: 10 separate dispatches (verified path)
        dim3 block(256);
        dim3 grid(NBLK);
        sweep<0><<<grid, block, 0, stream>>>(y, ths, nullptr, nullptr, FB, UB, nullptr);
        uint2 *fi = FB, *ui = UB, *fo = FA, *uo = UA;
        for (int it = 1; it <= 8; ++it) {
            sweep<1><<<grid, block, 0, stream>>>(y, ths, fi, ui, fo, uo, nullptr);
            uint2* t;
            t = fi; fi = fo; fo = t;
            t = ui; ui = uo; uo = t;
        }
        sweep<2><<<grid, block, 0, stream>>>(y, ths, fi, ui, nullptr, nullptr, xout);
    }
}

// Round 9
// 164.261 us; speedup vs baseline: 7.8930x; 7.8930x over previous
//
#include <hip/hip_runtime.h>
#include <hip/hip_fp16.h>
#include <math.h>

#define HH 512
#define WW 512
#define BB 4
#define NPIX (BB * HH * WW)

#define HS 4                 // core rows per wave (R0 % 4 == 0)
#define NSX 9                // strips: 9 x 60 core cols >= 512
#define NBAND (HH / HS)      // 128
#define NWAVES (NSX * NBAND * BB)   // 4608
#define NBLK (NWAVES / 4)           // 1152

constexpr float TAUf   = 0.01f;
constexpr float RHOf   = 1.99f;
constexpr float SIGMAf = (float)(1.0 / 0.01 / 72.0);
constexpr float INV1PT = (float)(1.0 / 1.01);

__device__ __forceinline__ float SD(float v) { return __shfl_down(v, 1, 64); }  // lane+1
__device__ __forceinline__ float SUp(float v) { return __shfl_up(v, 1, 64); }   // lane-1

// Packed state record S (uint4, 16B/pixel):
//   .x = half2(x2, r0), .y = half2(r1, y), .z = half2(u0, u1), .w = half2(u2, u3)
// y bits pass through unchanged every iteration (no re-rounding drift).

// MODE: 0 = init (x2=y, r=0, u=0); 1 = mid; 2 = final (x-only, f32 out)
template <int MODE>
__global__ __launch_bounds__(256) void sweep(
    const float* __restrict__ y, const int* __restrict__ ths_p,
    const uint4* __restrict__ s_in, uint4* __restrict__ s_out,
    float* __restrict__ xout)
{
    const int tid  = threadIdx.x;
    const int lane = tid & 63;
    const int wid  = blockIdx.x * 4 + (tid >> 6);
    const int sx   = wid % NSX;
    const int t2   = wid / NSX;
    const int band = t2 & (NBAND - 1);
    const int b    = t2 / NBAND;
    const int R0   = band * HS;               // multiple of 4 -> compile-time ring slots
    const int w    = sx * 60 - 2 + lane;
    const int boff = b * (HH * WW);
    const bool wok = ((unsigned)w) < (unsigned)WW;
    const float mA = (w >= 1 && w < WW) ? 1.f : 0.f;
    const float mB = (w >= 0 && w < WW - 1) ? 1.f : 0.f;
    const bool cok = (lane >= 2) && (lane < 62) && (w < WW);

    const float ths  = (float)ths_p[0];
    const float tl1_ = TAUf * (ths * 0.1f);   // rinv = min(tl1_*rsq(d), 1)
    const float l2_  = ths * 0.15f;           // ui   = min(l2_ *rsq(d), 1)

    // register rings
    float uf0[4], uf1[4], uf2[4], uf3[4];     // u rows (unpacked f32), slot row&3
    float i0r[2], i1r[2];                     // eps2_adj rows
    float sr[2], t1r[2];                      // s, t1 rows (row&1)
    float v0r[4], v1r[2];                     // v0(row) slot row&3, v1(row) slot row&1
    uint2 fring[4];                           // packed F-out; write slot (k+1)&3 at
                                              // stage k, read slot (k+3)&3 at stage k
                                              // (lag 2, 4 slots: producer runs first)
    #pragma unroll
    for (int q = 0; q < 4; ++q) {
        uf0[q]=uf1[q]=uf2[q]=uf3[q]=0.f; v0r[q]=0.f;
        fring[q].x = 0u; fring[q].y = 0u;
    }
    i0r[0]=i0r[1]=i1r[0]=i1r[1]=0.f;
    sr[0]=sr[1]=0.f; t1r[0]=t1r[1]=0.f; v1r[0]=v1r[1]=0.f;

    auto sload = [&](int row) -> uint4 {
        uint4 z; z.x = z.y = z.z = z.w = 0u;
        if (((unsigned)row) < (unsigned)HH && wok)
            z = s_in[(size_t)(boff + row * WW + w)];
        return z;
    };
    auto unpkU = [&](int slot, uint4 rec) {
        __half2 lo = *(reinterpret_cast<__half2*>(&rec.z));
        __half2 hi = *(reinterpret_cast<__half2*>(&rec.w));
        uf0[slot] = __low2float(lo); uf1[slot] = __high2float(lo);
        uf2[slot] = __low2float(hi); uf3[slot] = __high2float(hi);
    };
    // i(rr): islot, c = rr&3 (u row rr), d = (rr+1)&3, uu_ = (rr-1)&3
    auto compI = [&](int rr, int islot, int c, int d, int uu_) {
        if (((unsigned)rr) < (unsigned)HH) {
            float hD  = (rr < HH - 1) ? 1.f : 0.f;
            float u1c = uf1[c], u2c = uf2[c];
            i0r[islot] = uf0[c] - uf0[d] - SD(u1c) + mA * u1c;
            i1r[islot] = u2c - SD(u2c) - hD * uf3[c] + uf3[uu_];
        } else { i0r[islot] = 0.f; i1r[islot] = 0.f; }
    };

    if (MODE == 2) {
        // ---- final iter: x-only, f32 out; one record stream, 2-deep prefetch ----
        uint4 rm2 = sload(R0 - 2);
        uint4 rm1 = sload(R0 - 1);
        uint4 rc0 = sload(R0);
        unpkU(2, rm2); unpkU(3, rm1); unpkU(0, rc0);
        compI(R0 - 1, 1, 3, 0, 2);
        uint4 sF = rc0;               // F-extract row R0+k at stage k
        uint4 sA = sload(R0 + 1);     // u-unpack row R0+k+1 at stage k
        uint4 sB = sload(R0 + 2);
        #pragma unroll
        for (int k = 0; k < HS; ++k) {
            const int rr = R0 + k;
            uint4 nl; nl.x = nl.y = nl.z = nl.w = 0u;
            if (k < HS - 2) nl = sload(R0 + k + 3);
            unpkU((k + 1) & 3, sA);
            __half2 lo = *(reinterpret_cast<__half2*>(&sF.x));
            __half2 hi = *(reinterpret_cast<__half2*>(&sF.y));
            float x2v = __low2float(lo);
            float yv  = __high2float(hi);
            sF = sA; sA = sB; sB = nl;
            compI(rr, k & 1, k & 3, (k + 1) & 3, (k + 3) & 3);
            float hD = (rr < HH - 1) ? 1.f : 0.f;
            float i0c = i0r[k & 1], i1c = i1r[k & 1], i1u = i1r[(k + 1) & 1];
            float i0l = SUp(i0c);
            float na = TAUf * (mA * i0l - mB * i0c + i1u - hD * i1c);
            float x = (x2v - na + TAUf * yv) * INV1PT;
            if (cok) xout[boff + rr * WW + w] = x2v + RHOf * (x - x2v);
        }
        return;
    }

    // ---- prologue ----
    uint4 sF, sA, sB;
    sF.x=sF.y=sF.z=sF.w=0u; sA=sF; sB=sF;
    float pyA = 0.f, pyB = 0.f;
    if (MODE != 0) {
        uint4 a = sload(R0 - 3);
        uint4 c = sload(R0 - 2);
        uint4 d = sload(R0 - 1);
        unpkU(1, a); unpkU(2, c); unpkU(3, d);
        compI(R0 - 2, 0, 2, 3, 1);
        sF = d;                 // F-extract row R0-1 at k=0
        sA = sload(R0);         // u-unpack row R0 at k=0
        sB = sload(R0 + 1);
    } else {
        int rowA = R0 - 1; bool okA = (((unsigned)rowA) < (unsigned)HH) && wok;
        pyA = okA ? y[boff + rowA * WW + w] : 0.f;
        pyB = wok ? y[boff + R0 * WW + w] : 0.f;   // row R0 always valid
    }

    // ---- main pipeline: rr = R0-1 .. R0+HS+1 ----
    // slot algebra (R0 % 4 == 0, rr = R0-1+k):
    //   rr&1 = (k+1)&1, (rr-1)&1 = k&1, rr&3 = (k+3)&3
    //   ro = rr-2: ro&3 = (k+1)&3, (ro-1)&3 = k&3, ro&1 = (k+1)&1, (ro+1)&1 = k&1
    #pragma unroll
    for (int k = 0; k < HS + 3; ++k) {
        const int rr = R0 - 1 + k;

        float yv, x2v = 0.f, r20v = 0.f, r21v = 0.f; unsigned yraw = 0u;
        if (MODE != 0) {
            uint4 nl; nl.x = nl.y = nl.z = nl.w = 0u;
            if (k <= HS) nl = sload(R0 + k + 2);   // u at k+2, F at k+3
            unpkU(k & 3, sA);                      // u row R0+k
            __half2 lo = *(reinterpret_cast<__half2*>(&sF.x));
            __half2 hi = *(reinterpret_cast<__half2*>(&sF.y));
            x2v  = __low2float(lo);  r20v = __high2float(lo);
            r21v = __low2float(hi);  yv   = __high2float(hi);
            yraw = sF.y >> 16;
            sF = sA; sA = sB; sB = nl;
        } else {
            yv = pyA;
            pyA = pyB;
            if (k <= HS) {
                int row = R0 + k + 1;
                bool ok = (((unsigned)row) < (unsigned)HH) && wok;
                pyB = ok ? y[boff + row * WW + w] : 0.f;
            }
        }
        if (MODE != 0) compI(rr, (k + 1) & 1, (k + 3) & 3, k & 3, (k + 2) & 3);

        // compS: s,t(rr); pack F-out into fring on core rows (store deferred to compU)
        float sN, t0N, t1N;
        {
            const bool coreRow = (k >= 1 && k <= HS);
            if (((unsigned)rr) < (unsigned)HH) {
                if (MODE == 0) {
                    sN = yv; t0N = 0.f; t1N = 0.f;
                    if (coreRow) {
                        unsigned hb = (unsigned)__half_as_ushort(__float2half(yv));
                        fring[(k + 1) & 3].x = hb;          // {x2=y, r0=0}
                        fring[(k + 1) & 3].y = hb << 16;    // {r1=0, y}
                    }
                } else {
                    float hD = (rr < HH - 1) ? 1.f : 0.f;
                    float i0c = i0r[(k + 1) & 1], i1c = i1r[(k + 1) & 1];
                    float i1u = i1r[k & 1];
                    float i0l = SUp(i0c);
                    float na = TAUf * (mA * i0l - mB * i0c + i1u - hD * i1c);
                    float x = (x2v - na + TAUf * yv) * INV1PT;
                    float rr0 = r20v + TAUf * i0c;
                    float rr1 = r21v + TAUf * i1c;
                    float dd = rr0 * rr0 + rr1 * rr1;
                    float rinv = fminf(tl1_ * __builtin_amdgcn_rsqf(dd), 1.0f);
                    float r0 = rr0 - rr0 * rinv;
                    float r1 = rr1 - rr1 * rinv;
                    sN  = 2.f * x  - x2v;
                    t0N = 2.f * r0 - r20v;
                    t1N = 2.f * r1 - r21v;
                    if (coreRow) {
                        __half2 lo2 = __floats2half2_rn(x2v + RHOf * (x - x2v),
                                                        r20v + RHOf * (r0 - r20v));
                        unsigned r1b = (unsigned)__half_as_ushort(
                            __float2half(r21v + RHOf * (r1 - r21v)));
                        fring[(k + 1) & 3].x = *(unsigned*)&lo2;
                        fring[(k + 1) & 3].y = r1b | (yraw << 16);
                    }
                }
            } else { sN = 0.f; t0N = 0.f; t1N = 0.f; }
        }

        // v-ring updates for row rr (v0) and row rr-1 (v1)
        {
            float sPrev  = sr[k & 1];
            float t1Prev = t1r[k & 1];
            float hDm1   = (rr < HH) ? 1.f : 0.f;
            v0r[(k + 3) & 3] = mB * (SD(sN) - sN) - t0N;
            v1r[k & 1]       = hDm1 * (sN - sPrev) - t1Prev;
            sr[(k + 1) & 1]  = sN;
            t1r[(k + 1) & 1] = t1N;
        }

        if (k >= 3) {
            // compU(ro = R0-3+k) + combined 16B store {F(ro), u'(ro)}
            // fring for row ro was written at stage k-2 into slot (k-1)&3 = (k+3)&3
            const int ro = R0 - 3 + k;
            float hD  = (ro < HH - 1) ? 1.f : 0.f;
            float v0c = v0r[(k + 1) & 3], v0u = v0r[k & 3];
            float v1c = v1r[(k + 1) & 1], v1d = v1r[k & 1];
            float v0l = SUp(v0c);
            float v1l = SUp(v1c);
            float G0 = v0c - v0u;
            float G1 = mA * (v0c - v0l);
            float G2 = v1c - mA * v1l;
            float G3 = hD * (v1d - v1c);
            float u0v, u1v, u2v, u3v;
            if (MODE == 0) { u0v = u1v = u2v = u3v = 0.f; }
            else {
                const int us = (k + 1) & 3;
                u0v = uf0[us]; u1v = uf1[us]; u2v = uf2[us]; u3v = uf3[us];
            }
            float uu0 = u0v + SIGMAf * G0;
            float uu1 = u1v + SIGMAf * G1;
            float uu2 = u2v + SIGMAf * G2;
            float uu3 = u3v + SIGMAf * G3;
            float dd = uu0 * uu0 + uu1 * uu1 + uu2 * uu2 + uu3 * uu3;
            float uiS = fminf(l2_ * __builtin_amdgcn_rsqf(dd), 1.0f);
            if (cok) {
                int idx = boff + ro * WW + w;
                __half2 lo = __floats2half2_rn(u0v + RHOf * (uu0 * uiS - u0v),
                                               u1v + RHOf * (uu1 * uiS - u1v));
                __half2 hi = __floats2half2_rn(u2v + RHOf * (uu2 * uiS - u2v),
                                               u3v + RHOf * (uu3 * uiS - u3v));
                uint4 st;
                st.x = fring[(k + 3) & 3].x;
                st.y = fring[(k + 3) & 3].y;
                st.z = *(unsigned*)&lo;
                st.w = *(unsigned*)&hi;
                s_out[(size_t)idx] = st;
            }
        }
    }
}

extern "C" void kernel_launch(void* const* d_in, const int* in_sizes, int n_in,
                              void* d_out, int out_size, void* d_ws, size_t ws_size,
                              hipStream_t stream)
{
    const float* y   = (const float*)d_in[0];
    const int*   ths = (const int*)d_in[1];
    uint4* SA = (uint4*)d_ws;
    uint4* SB = SA + (size_t)NPIX;
    float* xout = (float*)d_out;

    dim3 block(256);
    dim3 grid(NBLK);

    // iter 0 (analytic) -> SB
    sweep<0><<<grid, block, 0, stream>>>(y, ths, nullptr, SB, nullptr);
    // iters 1..8 alternate
    uint4 *si = SB, *so = SA;
    for (int it = 1; it <= 8; ++it) {
        sweep<1><<<grid, block, 0, stream>>>(y, ths, si, so, nullptr);
        uint4* t = si; si = so; so = t;
    }
    // iter 9: x only -> d_out
    sweep<2><<<grid, block, 0, stream>>>(y, ths, si, nullptr, xout);
}